// Round 1
// baseline (3089.683 us; speedup 1.0000x reference)
//
#include <hip/hip_runtime.h>

#define NN 100000      // nodes
#define K1 500         // input features
#define F1 128         // hidden features
#define F2 64          // output features

// ---------------- degree (in-degree over col; self-loop added as +1 later) --
__global__ void k_deg(const int* __restrict__ col, int E, float* __restrict__ deg) {
    int e = blockIdx.x * blockDim.x + threadIdx.x;
    if (e < E) atomicAdd(&deg[col[e]], 1.0f);
}

__global__ void k_dinv(float* __restrict__ d, int n) {
    int i = blockIdx.x * blockDim.x + threadIdx.x;
    if (i < n) d[i] = rsqrtf(d[i] + 1.0f);   // deg includes +1 self loop; always > 0
}

// ---------------- GEMM1: h[NN,128] = x[NN,500] @ W1[500,128] ----------------
// 8 rows per 128-thread block; x rows staged in LDS (pad 500->504 for aligned float4)
__global__ __launch_bounds__(128) void k_gemm1(const float* __restrict__ x,
                                               const float* __restrict__ W,
                                               float* __restrict__ h) {
    __shared__ __align__(16) float xs[8 * 504];
    const int r0 = blockIdx.x * 8;
    const int j  = threadIdx.x;                 // output column 0..127
    for (int r = 0; r < 8; ++r)
        for (int i = j; i < K1; i += 128)
            xs[r * 504 + i] = x[(size_t)(r0 + r) * K1 + i];
    __syncthreads();

    float acc[8] = {0.f,0.f,0.f,0.f,0.f,0.f,0.f,0.f};
    for (int k = 0; k < K1; k += 4) {
        const float w0 = W[(k + 0) * F1 + j];
        const float w1 = W[(k + 1) * F1 + j];
        const float w2 = W[(k + 2) * F1 + j];
        const float w3 = W[(k + 3) * F1 + j];
#pragma unroll
        for (int r = 0; r < 8; ++r) {
            const float4 xv = *(const float4*)&xs[r * 504 + k];
            acc[r] += xv.x * w0 + xv.y * w1 + xv.z * w2 + xv.w * w3;
        }
    }
#pragma unroll
    for (int r = 0; r < 8; ++r)
        h[(size_t)(r0 + r) * F1 + j] = acc[r];
}

// ---------------- scatter aggregation: agg[col] += h[row]*norm --------------
// items [0,E) are real edges; items [E, E+n) are self loops (row=col=n).
// 32 lanes per item; F/32 coalesced 128B atomic bursts.
template <int F>
__global__ void k_agg(const int* __restrict__ row, const int* __restrict__ col,
                      int E, int n, const float* __restrict__ dinv,
                      const float* __restrict__ h, float* __restrict__ agg) {
    long t = (long)blockIdx.x * blockDim.x + threadIdx.x;
    int item = (int)(t >> 5);
    int l    = (int)(t & 31);
    if (item >= E + n) return;
    int r, c;
    if (item < E) { r = row[item]; c = col[item]; }
    else          { r = c = item - E; }
    const float norm = dinv[r] * dinv[c];
    const float* hr = h   + (size_t)r * F;
    float*       ac = agg + (size_t)c * F;
#pragma unroll
    for (int s = 0; s < F / 32; ++s) {
        int f = l + 32 * s;
        atomicAdd(&ac[f], hr[f] * norm);
    }
}

// ---------------- GEMM2: h2[NN,64] = relu(agg1 + b1) @ W2[128,64] -----------
// 64 rows per 256-thread block; W2 (32KB) + activated rows (32KB) in LDS.
__global__ __launch_bounds__(256) void k_gemm2(const float* __restrict__ agg1,
                                               const float* __restrict__ b1,
                                               const float* __restrict__ W2,
                                               float* __restrict__ h2) {
    __shared__ __align__(16) float W2s[F1 * F2];
    __shared__ __align__(16) float xs[64 * F1];
    const int tid = threadIdx.x;
    const int r0  = blockIdx.x * 64;
    for (int i = tid; i < F1 * F2; i += 256) W2s[i] = W2[i];
    const int base = r0 * F1;
    for (int i = tid; i < 64 * F1; i += 256) {
        int gi = base + i;
        float v = 0.f;
        if (gi < NN * F1) v = fmaxf(agg1[gi] + b1[i & (F1 - 1)], 0.f);
        xs[i] = v;
    }
    __syncthreads();

    const int j = tid & 63;      // output column
    const int g = tid >> 6;      // wave id -> rows g*16 .. g*16+15
    float acc[16];
#pragma unroll
    for (int rr = 0; rr < 16; ++rr) acc[rr] = 0.f;

    for (int k = 0; k < F1; k += 4) {
        const float w0 = W2s[(k + 0) * F2 + j];
        const float w1 = W2s[(k + 1) * F2 + j];
        const float w2 = W2s[(k + 2) * F2 + j];
        const float w3 = W2s[(k + 3) * F2 + j];
#pragma unroll
        for (int rr = 0; rr < 16; ++rr) {
            const float4 xv = *(const float4*)&xs[(g * 16 + rr) * F1 + k];
            acc[rr] += xv.x * w0 + xv.y * w1 + xv.z * w2 + xv.w * w3;
        }
    }
#pragma unroll
    for (int rr = 0; rr < 16; ++rr) {
        int r = r0 + g * 16 + rr;
        if (r < NN) h2[(size_t)r * F2 + j] = acc[rr];
    }
}

// ---------------- decode: out[e] = dot(z[src]+b2, z[dst]+b2) over 64 dims ---
// 16 lanes per edge, float4 per lane, shfl reduce over width 16.
__global__ void k_decode(const int* __restrict__ src, const int* __restrict__ dst,
                         int E, const float* __restrict__ z,
                         const float* __restrict__ b2, float* __restrict__ out) {
    long t = (long)blockIdx.x * blockDim.x + threadIdx.x;
    int e = (int)(t >> 4);
    int l = (int)(t & 15);
    if (e >= E) return;
    const int s = src[e], d = dst[e];
    const float4 zs = *(const float4*)&z[(size_t)s * F2 + l * 4];
    const float4 zd = *(const float4*)&z[(size_t)d * F2 + l * 4];
    const float4 bb = *(const float4*)&b2[l * 4];
    float v = (zs.x + bb.x) * (zd.x + bb.x)
            + (zs.y + bb.y) * (zd.y + bb.y)
            + (zs.z + bb.z) * (zd.z + bb.z)
            + (zs.w + bb.w) * (zd.w + bb.w);
#pragma unroll
    for (int off = 8; off; off >>= 1) v += __shfl_down(v, off, 16);
    if (l == 0) out[e] = v;
}

extern "C" void kernel_launch(void* const* d_in, const int* in_sizes, int n_in,
                              void* d_out, int out_size, void* d_ws, size_t ws_size,
                              hipStream_t stream) {
    const float* x  = (const float*)d_in[0];
    const float* W1 = (const float*)d_in[1];
    const float* b1 = (const float*)d_in[2];
    const float* W2 = (const float*)d_in[3];
    const float* b2 = (const float*)d_in[4];
    const int*   ei = (const int*)d_in[5];
    const int E = in_sizes[5] / 2;
    const int* rowp = ei;        // edge_index[0] = source (gather side)
    const int* colp = ei + E;    // edge_index[1] = destination (scatter side)

    float* ws   = (float*)d_ws;
    float* dinv = ws;                       // NN floats
    float* bufA = ws + 100352;              // 12.8M floats: h, then h2
    float* bufB = bufA + (size_t)NN * F1;   // 12.8M floats: agg1/h1, then agg2/z
    float* out  = (float*)d_out;

    // zero deg and agg1 (ws is poisoned 0xAA before every call)
    hipMemsetAsync(dinv, 0, (size_t)NN * sizeof(float), stream);
    hipMemsetAsync(bufB, 0, (size_t)NN * F1 * sizeof(float), stream);

    k_deg<<<(E + 255) / 256, 256, 0, stream>>>(colp, E, dinv);
    k_dinv<<<(NN + 255) / 256, 256, 0, stream>>>(dinv, NN);

    k_gemm1<<<NN / 8, 128, 0, stream>>>(x, W1, bufA);

    const long items = ((long)E + NN) * 32;
    k_agg<F1><<<(int)((items + 255) / 256), 256, 0, stream>>>(
        rowp, colp, E, NN, dinv, bufA, bufB);

    k_gemm2<<<(NN + 63) / 64, 256, 0, stream>>>(bufB, b1, W2, bufA);

    hipMemsetAsync(bufB, 0, (size_t)NN * F2 * sizeof(float), stream);
    k_agg<F2><<<(int)((items + 255) / 256), 256, 0, stream>>>(
        rowp, colp, E, NN, dinv, bufA, bufB);

    const long dthreads = (long)E * 16;
    k_decode<<<(int)((dthreads + 255) / 256), 256, 0, stream>>>(
        rowp, colp, E, bufB, b2, out);
}

// Round 2
// 1684.641 us; speedup vs baseline: 1.8340x; 1.8340x over previous
//
#include <hip/hip_runtime.h>

#define NN 100000      // nodes
#define K1 500         // input features
#define F1 128         // hidden features
#define F2 64          // output features
#define NB ((NN + 255) / 256)   // scan blocks = 391

// ---------------- CSR build ----------------
__global__ void k_hist(const int* __restrict__ col, int E, int* __restrict__ cnt) {
    int e = blockIdx.x * blockDim.x + threadIdx.x;
    if (e < E) atomicAdd(&cnt[col[e]], 1);
}

// block-local exclusive scan of cnt -> ptr, block sums -> part, dinv = rsqrt(cnt+1)
__global__ __launch_bounds__(256) void k_scan1(const int* __restrict__ cnt,
                                               int* __restrict__ ptr,
                                               int* __restrict__ part,
                                               float* __restrict__ dinv) {
    __shared__ int s[256];
    const int tid = threadIdx.x;
    const int i = blockIdx.x * 256 + tid;
    int v = (i < NN) ? cnt[i] : 0;
    if (i < NN) dinv[i] = rsqrtf((float)v + 1.0f);   // +1 self loop
    s[tid] = v;
    __syncthreads();
    for (int off = 1; off < 256; off <<= 1) {
        int t = (tid >= off) ? s[tid - off] : 0;
        __syncthreads();
        s[tid] += t;
        __syncthreads();
    }
    if (i < NN) ptr[i] = s[tid] - v;                  // exclusive, block-local
    if (tid == 255) part[blockIdx.x] = s[255];
}

// single-block exclusive scan of the 391 block sums
__global__ __launch_bounds__(512) void k_scan2(int* __restrict__ part, int nb) {
    __shared__ int s[512];
    const int tid = threadIdx.x;
    int v = (tid < nb) ? part[tid] : 0;
    s[tid] = v;
    __syncthreads();
    for (int off = 1; off < 512; off <<= 1) {
        int t = (tid >= off) ? s[tid - off] : 0;
        __syncthreads();
        s[tid] += t;
        __syncthreads();
    }
    if (tid < nb) part[tid] = s[tid] - v;             // exclusive
}

__global__ __launch_bounds__(256) void k_scan3(int* __restrict__ ptr,
                                               const int* __restrict__ part,
                                               int* __restrict__ cursor) {
    const int i = blockIdx.x * 256 + threadIdx.x;
    if (i < NN) {
        int p = ptr[i] + part[blockIdx.x];
        ptr[i] = p;
        cursor[i] = p;
    }
}

__global__ void k_fill(const int* __restrict__ row, const int* __restrict__ col,
                       int E, int* __restrict__ cursor, int* __restrict__ idx) {
    int e = blockIdx.x * blockDim.x + threadIdx.x;
    if (e < E) {
        int p = atomicAdd(&cursor[col[e]], 1);
        idx[p] = row[e];
    }
}

// ---------------- GEMM1: h[NN,128] = x[NN,500] @ W1[500,128] ----------------
__global__ __launch_bounds__(128) void k_gemm1(const float* __restrict__ x,
                                               const float* __restrict__ W,
                                               float* __restrict__ h) {
    __shared__ __align__(16) float xs[8 * 504];
    const int r0 = blockIdx.x * 8;
    const int j  = threadIdx.x;                 // output column 0..127
    for (int r = 0; r < 8; ++r)
        for (int i = j; i < K1; i += 128)
            xs[r * 504 + i] = x[(size_t)(r0 + r) * K1 + i];
    __syncthreads();

    float acc[8] = {0.f,0.f,0.f,0.f,0.f,0.f,0.f,0.f};
    for (int k = 0; k < K1; k += 4) {
        const float w0 = W[(k + 0) * F1 + j];
        const float w1 = W[(k + 1) * F1 + j];
        const float w2 = W[(k + 2) * F1 + j];
        const float w3 = W[(k + 3) * F1 + j];
#pragma unroll
        for (int r = 0; r < 8; ++r) {
            const float4 xv = *(const float4*)&xs[r * 504 + k];
            acc[r] += xv.x * w0 + xv.y * w1 + xv.z * w2 + xv.w * w3;
        }
    }
#pragma unroll
    for (int r = 0; r < 8; ++r)
        h[(size_t)(r0 + r) * F1 + j] = acc[r];
}

// ---------------- pull aggregation: agg[c] = sum_{r in N(c)} h[r]*dinv_r*dinv_c + h[c]*dinv_c^2
template <int F>
__global__ __launch_bounds__(256) void k_agg_pull(const int* __restrict__ ptr,
                                                  const int* __restrict__ idx, int E,
                                                  const float* __restrict__ dinv,
                                                  const float* __restrict__ h,
                                                  float* __restrict__ agg) {
    constexpr int NPB = 256 / F;                 // nodes per block
    const int c = blockIdx.x * NPB + threadIdx.x / F;
    const int f = threadIdx.x % F;
    if (c >= NN) return;
    const float dc = dinv[c];
    const int s   = ptr[c];
    const int end = (c + 1 < NN) ? ptr[c + 1] : E;
    float acc = h[(size_t)c * F + f] * dc * dc;  // self loop
    int e = s;
    for (; e + 4 <= end; e += 4) {
        const int r0 = idx[e], r1 = idx[e + 1], r2 = idx[e + 2], r3 = idx[e + 3];
        const float w0 = dinv[r0] * dc, w1 = dinv[r1] * dc;
        const float w2 = dinv[r2] * dc, w3 = dinv[r3] * dc;
        acc += h[(size_t)r0 * F + f] * w0;
        acc += h[(size_t)r1 * F + f] * w1;
        acc += h[(size_t)r2 * F + f] * w2;
        acc += h[(size_t)r3 * F + f] * w3;
    }
    for (; e < end; ++e) {
        const int r = idx[e];
        acc += h[(size_t)r * F + f] * (dinv[r] * dc);
    }
    agg[(size_t)c * F + f] = acc;
}

// ---------------- GEMM2: h2[NN,64] = relu(agg1 + b1) @ W2[128,64] -----------
__global__ __launch_bounds__(256) void k_gemm2(const float* __restrict__ agg1,
                                               const float* __restrict__ b1,
                                               const float* __restrict__ W2,
                                               float* __restrict__ h2) {
    __shared__ __align__(16) float W2s[F1 * F2];
    __shared__ __align__(16) float xs[64 * F1];
    const int tid = threadIdx.x;
    const int r0  = blockIdx.x * 64;
    for (int i = tid; i < F1 * F2; i += 256) W2s[i] = W2[i];
    const int base = r0 * F1;
    for (int i = tid; i < 64 * F1; i += 256) {
        int gi = base + i;
        float v = 0.f;
        if (gi < NN * F1) v = fmaxf(agg1[gi] + b1[i & (F1 - 1)], 0.f);
        xs[i] = v;
    }
    __syncthreads();

    const int j = tid & 63;      // output column
    const int g = tid >> 6;      // wave id -> rows g*16 .. g*16+15
    float acc[16];
#pragma unroll
    for (int rr = 0; rr < 16; ++rr) acc[rr] = 0.f;

    for (int k = 0; k < F1; k += 4) {
        const float w0 = W2s[(k + 0) * F2 + j];
        const float w1 = W2s[(k + 1) * F2 + j];
        const float w2 = W2s[(k + 2) * F2 + j];
        const float w3 = W2s[(k + 3) * F2 + j];
#pragma unroll
        for (int rr = 0; rr < 16; ++rr) {
            const float4 xv = *(const float4*)&xs[(g * 16 + rr) * F1 + k];
            acc[rr] += xv.x * w0 + xv.y * w1 + xv.z * w2 + xv.w * w3;
        }
    }
#pragma unroll
    for (int rr = 0; rr < 16; ++rr) {
        int r = r0 + g * 16 + rr;
        if (r < NN) h2[(size_t)r * F2 + j] = acc[rr];
    }
}

// ---------------- decode: out[e] = dot(z[src]+b2, z[dst]+b2) over 64 dims ---
__global__ void k_decode(const int* __restrict__ src, const int* __restrict__ dst,
                         int E, const float* __restrict__ z,
                         const float* __restrict__ b2, float* __restrict__ out) {
    long t = (long)blockIdx.x * blockDim.x + threadIdx.x;
    int e = (int)(t >> 4);
    int l = (int)(t & 15);
    if (e >= E) return;
    const int s = src[e], d = dst[e];
    const float4 zs = *(const float4*)&z[(size_t)s * F2 + l * 4];
    const float4 zd = *(const float4*)&z[(size_t)d * F2 + l * 4];
    const float4 bb = *(const float4*)&b2[l * 4];
    float v = (zs.x + bb.x) * (zd.x + bb.x)
            + (zs.y + bb.y) * (zd.y + bb.y)
            + (zs.z + bb.z) * (zd.z + bb.z)
            + (zs.w + bb.w) * (zd.w + bb.w);
#pragma unroll
    for (int off = 8; off; off >>= 1) v += __shfl_down(v, off, 16);
    if (l == 0) out[e] = v;
}

extern "C" void kernel_launch(void* const* d_in, const int* in_sizes, int n_in,
                              void* d_out, int out_size, void* d_ws, size_t ws_size,
                              hipStream_t stream) {
    const float* x  = (const float*)d_in[0];
    const float* W1 = (const float*)d_in[1];
    const float* b1 = (const float*)d_in[2];
    const float* W2 = (const float*)d_in[3];
    const float* b2 = (const float*)d_in[4];
    const int*   ei = (const int*)d_in[5];
    const int E = in_sizes[5] / 2;
    const int* rowp = ei;        // edge_index[0] = source (gather side)
    const int* colp = ei + E;    // edge_index[1] = destination (scatter side)

    // ---- workspace layout (4-byte units, 100352 = NN padded) ----
    char* wsb = (char*)d_ws;
    float* dinv   = (float*)wsb;                          wsb += 100352 * 4;
    int*   cnt    = (int*)wsb;                            wsb += 100352 * 4;
    int*   ptr    = (int*)wsb;                            wsb += 100352 * 4;
    int*   cursor = (int*)wsb;                            wsb += 100352 * 4;
    int*   part   = (int*)wsb;                            wsb += 512 * 4;
    int*   idx    = (int*)wsb;                            wsb += (size_t)E * 4;
    float* bufA   = (float*)wsb;                          wsb += (size_t)NN * F1 * 4;
    float* bufB   = (float*)wsb;
    float* out    = (float*)d_out;

    // ---- CSR build ----
    hipMemsetAsync(cnt, 0, (size_t)NN * sizeof(int), stream);
    k_hist<<<(E + 255) / 256, 256, 0, stream>>>(colp, E, cnt);
    k_scan1<<<NB, 256, 0, stream>>>(cnt, ptr, part, dinv);
    k_scan2<<<1, 512, 0, stream>>>(part, NB);
    k_scan3<<<NB, 256, 0, stream>>>(ptr, part, cursor);
    k_fill<<<(E + 255) / 256, 256, 0, stream>>>(rowp, colp, E, cursor, idx);

    // ---- layer 1 ----
    k_gemm1<<<NN / 8, 128, 0, stream>>>(x, W1, bufA);
    k_agg_pull<F1><<<(NN + 1) / 2, 256, 0, stream>>>(ptr, idx, E, dinv, bufA, bufB);

    // ---- layer 2 ----
    k_gemm2<<<(NN + 63) / 64, 256, 0, stream>>>(bufB, b1, W2, bufA);
    k_agg_pull<F2><<<(NN + 3) / 4, 256, 0, stream>>>(ptr, idx, E, dinv, bufA, bufB);

    // ---- decode ----
    const long dthreads = (long)E * 16;
    k_decode<<<(int)((dthreads + 255) / 256), 256, 0, stream>>>(
        rowp, colp, E, bufB, b2, out);
}

// Round 3
// 1338.443 us; speedup vs baseline: 2.3084x; 1.2587x over previous
//
#include <hip/hip_runtime.h>

#define NN 100000      // nodes
#define K1 500         // input features
#define F1 128         // hidden features
#define F2 64          // output features
#define NB ((NN + 255) / 256)   // scan blocks = 391

typedef __attribute__((ext_vector_type(8))) short short8;
typedef __attribute__((ext_vector_type(4))) float floatx4;

static __device__ __forceinline__ unsigned short f2bf(float f) {
    unsigned int u = __float_as_uint(f);
    unsigned int r = (u + 0x7FFF + ((u >> 16) & 1)) >> 16;   // RNE
    return (unsigned short)r;
}
static __device__ __forceinline__ float ldh(const unsigned short* p) {
    return __uint_as_float(((unsigned int)*p) << 16);
}
static __device__ __forceinline__ float ldh(const float* p) { return *p; }

// ---------------- CSR build ----------------
__global__ void k_hist(const int* __restrict__ col, int E, int* __restrict__ cnt) {
    int e = blockIdx.x * blockDim.x + threadIdx.x;
    if (e < E) atomicAdd(&cnt[col[e]], 1);
}

__global__ __launch_bounds__(256) void k_scan1(const int* __restrict__ cnt,
                                               int* __restrict__ ptr,
                                               int* __restrict__ part,
                                               float* __restrict__ dinv) {
    __shared__ int s[256];
    const int tid = threadIdx.x;
    const int i = blockIdx.x * 256 + tid;
    int v = (i < NN) ? cnt[i] : 0;
    if (i < NN) dinv[i] = rsqrtf((float)v + 1.0f);   // +1 self loop
    s[tid] = v;
    __syncthreads();
    for (int off = 1; off < 256; off <<= 1) {
        int t = (tid >= off) ? s[tid - off] : 0;
        __syncthreads();
        s[tid] += t;
        __syncthreads();
    }
    if (i < NN) ptr[i] = s[tid] - v;                  // exclusive, block-local
    if (tid == 255) part[blockIdx.x] = s[255];
}

__global__ __launch_bounds__(512) void k_scan2(int* __restrict__ part, int nb) {
    __shared__ int s[512];
    const int tid = threadIdx.x;
    int v = (tid < nb) ? part[tid] : 0;
    s[tid] = v;
    __syncthreads();
    for (int off = 1; off < 512; off <<= 1) {
        int t = (tid >= off) ? s[tid - off] : 0;
        __syncthreads();
        s[tid] += t;
        __syncthreads();
    }
    if (tid < nb) part[tid] = s[tid] - v;             // exclusive
}

__global__ __launch_bounds__(256) void k_scan3(int* __restrict__ ptr,
                                               const int* __restrict__ part,
                                               int* __restrict__ cursor) {
    const int i = blockIdx.x * 256 + threadIdx.x;
    if (i < NN) {
        int p = ptr[i] + part[blockIdx.x];
        ptr[i] = p;
        cursor[i] = p;
    }
}

__global__ void k_fill(const int* __restrict__ row, const int* __restrict__ col,
                       int E, int* __restrict__ cursor, int* __restrict__ idx) {
    int e = blockIdx.x * blockDim.x + threadIdx.x;
    if (e < E) {
        int p = atomicAdd(&cursor[col[e]], 1);
        idx[p] = row[e];
    }
}

// ---------------- W1T: [500][128] fp32 -> [128][512] bf16 (zero pad) -------
__global__ __launch_bounds__(256) void k_w1t(const float* __restrict__ W1,
                                             unsigned short* __restrict__ W1T) {
    int t = blockIdx.x * 256 + threadIdx.x;   // 128*512 = 65536
    int n = t >> 9, k = t & 511;
    W1T[t] = (k < K1) ? f2bf(W1[k * F1 + n]) : (unsigned short)0;
}

// ---------------- GEMM1 (MFMA bf16): h[NN,128] = x[NN,500] @ W1 ------------
// Register-fragment, LDS-free. Block = 128-row stripe; wave w: rows w*32..+32.
// 2 m-tiles x 8 n-tiles of 16x16x32, K padded 500->512 (masked epilogue).
__global__ __launch_bounds__(256) void k_gemm1_mfma(
    const float* __restrict__ x,
    const unsigned short* __restrict__ W1T,   // [128][512] bf16
    unsigned short* __restrict__ h)           // [NN][128] bf16
{
    const int wave = threadIdx.x >> 6;
    const int lane = threadIdx.x & 63;
    const int q    = lane >> 4;          // quad: k-offset q*8
    const int m16  = lane & 15;
    const int rowBase = blockIdx.x * 128 + wave * 32;

    floatx4 acc[2][8];
#pragma unroll
    for (int a = 0; a < 2; ++a)
#pragma unroll
        for (int b = 0; b < 8; ++b) acc[a][b] = (floatx4){0.f, 0.f, 0.f, 0.f};

    int row0 = rowBase + m16;      if (row0 > NN - 1) row0 = NN - 1;
    int row1 = rowBase + 16 + m16; if (row1 > NN - 1) row1 = NN - 1;
    const size_t rb[2] = {(size_t)row0 * K1, (size_t)row1 * K1};

#pragma unroll 3
    for (int k0 = 0; k0 < 480; k0 += 32) {
        const int kk = k0 + q * 8;
        short8 afr[2], bfr[8];
#pragma unroll
        for (int mt = 0; mt < 2; ++mt) {
            const floatx4 v0 = *(const floatx4*)(x + rb[mt] + kk);
            const floatx4 v1 = *(const floatx4*)(x + rb[mt] + kk + 4);
            short8 t;
            t[0] = f2bf(v0[0]); t[1] = f2bf(v0[1]); t[2] = f2bf(v0[2]); t[3] = f2bf(v0[3]);
            t[4] = f2bf(v1[0]); t[5] = f2bf(v1[1]); t[6] = f2bf(v1[2]); t[7] = f2bf(v1[3]);
            afr[mt] = t;
        }
#pragma unroll
        for (int nt = 0; nt < 8; ++nt)
            bfr[nt] = *(const short8*)(W1T + (nt * 16 + m16) * 512 + kk);
#pragma unroll
        for (int mt = 0; mt < 2; ++mt)
#pragma unroll
            for (int nt = 0; nt < 8; ++nt)
                acc[mt][nt] = __builtin_amdgcn_mfma_f32_16x16x32_bf16(
                    afr[mt], bfr[nt], acc[mt][nt], 0, 0, 0);
    }
    {   // K epilogue: k0 = 480, mask k >= 500 (W1T pad is already zero)
        const int kk = 480 + q * 8;
        short8 afr[2], bfr[8];
#pragma unroll
        for (int mt = 0; mt < 2; ++mt) {
            short8 t;
#pragma unroll
            for (int j = 0; j < 8; ++j) {
                const int k = kk + j;
                t[j] = (k < K1) ? (short)f2bf(x[rb[mt] + k]) : (short)0;
            }
            afr[mt] = t;
        }
#pragma unroll
        for (int nt = 0; nt < 8; ++nt)
            bfr[nt] = *(const short8*)(W1T + (nt * 16 + m16) * 512 + kk);
#pragma unroll
        for (int mt = 0; mt < 2; ++mt)
#pragma unroll
            for (int nt = 0; nt < 8; ++nt)
                acc[mt][nt] = __builtin_amdgcn_mfma_f32_16x16x32_bf16(
                    afr[mt], bfr[nt], acc[mt][nt], 0, 0, 0);
    }
    // store: C/D layout col = lane&15, row = q*4 + reg
#pragma unroll
    for (int mt = 0; mt < 2; ++mt) {
        const int rbase = rowBase + mt * 16 + q * 4;
#pragma unroll
        for (int nt = 0; nt < 8; ++nt) {
            const int col = nt * 16 + m16;
#pragma unroll
            for (int r = 0; r < 4; ++r) {
                const int row = rbase + r;
                if (row < NN) h[(size_t)row * F1 + col] = f2bf(acc[mt][nt][r]);
            }
        }
    }
}

// ---------------- pull aggregation ----------------
template <int F, typename T>
__global__ __launch_bounds__(256) void k_agg_pull(const int* __restrict__ ptr,
                                                  const int* __restrict__ idx, int E,
                                                  const float* __restrict__ dinv,
                                                  const T* __restrict__ h,
                                                  float* __restrict__ agg) {
    constexpr int NPB = 256 / F;                 // nodes per block
    const int c = blockIdx.x * NPB + threadIdx.x / F;
    const int f = threadIdx.x % F;
    if (c >= NN) return;
    const float dc = dinv[c];
    const int s   = ptr[c];
    const int end = (c + 1 < NN) ? ptr[c + 1] : E;
    float acc = ldh(&h[(size_t)c * F + f]) * dc * dc;  // self loop
    int e = s;
    for (; e + 4 <= end; e += 4) {
        const int r0 = idx[e], r1 = idx[e + 1], r2 = idx[e + 2], r3 = idx[e + 3];
        const float w0 = dinv[r0] * dc, w1 = dinv[r1] * dc;
        const float w2 = dinv[r2] * dc, w3 = dinv[r3] * dc;
        acc += ldh(&h[(size_t)r0 * F + f]) * w0;
        acc += ldh(&h[(size_t)r1 * F + f]) * w1;
        acc += ldh(&h[(size_t)r2 * F + f]) * w2;
        acc += ldh(&h[(size_t)r3 * F + f]) * w3;
    }
    for (; e < end; ++e) {
        const int r = idx[e];
        acc += ldh(&h[(size_t)r * F + f]) * (dinv[r] * dc);
    }
    agg[(size_t)c * F + f] = acc;
}

// ---------------- GEMM2: h2[NN,64] = relu(agg1 + b1) @ W2[128,64] -----------
__global__ __launch_bounds__(256) void k_gemm2(const float* __restrict__ agg1,
                                               const float* __restrict__ b1,
                                               const float* __restrict__ W2,
                                               float* __restrict__ h2) {
    __shared__ __align__(16) float W2s[F1 * F2];
    __shared__ __align__(16) float xs[64 * F1];
    const int tid = threadIdx.x;
    const int r0  = blockIdx.x * 64;
    for (int i = tid; i < F1 * F2; i += 256) W2s[i] = W2[i];
    const int base = r0 * F1;
    for (int i = tid; i < 64 * F1; i += 256) {
        int gi = base + i;
        float v = 0.f;
        if (gi < NN * F1) v = fmaxf(agg1[gi] + b1[i & (F1 - 1)], 0.f);
        xs[i] = v;
    }
    __syncthreads();

    const int j = tid & 63;      // output column
    const int g = tid >> 6;      // wave id -> rows g*16 .. g*16+15
    float acc[16];
#pragma unroll
    for (int rr = 0; rr < 16; ++rr) acc[rr] = 0.f;

    for (int k = 0; k < F1; k += 4) {
        const float w0 = W2s[(k + 0) * F2 + j];
        const float w1 = W2s[(k + 1) * F2 + j];
        const float w2 = W2s[(k + 2) * F2 + j];
        const float w3 = W2s[(k + 3) * F2 + j];
#pragma unroll
        for (int rr = 0; rr < 16; ++rr) {
            const float4 xv = *(const float4*)&xs[(g * 16 + rr) * F1 + k];
            acc[rr] += xv.x * w0 + xv.y * w1 + xv.z * w2 + xv.w * w3;
        }
    }
#pragma unroll
    for (int rr = 0; rr < 16; ++rr) {
        int r = r0 + g * 16 + rr;
        if (r < NN) h2[(size_t)r * F2 + j] = acc[rr];
    }
}

// ---------------- decode: out[e] = dot(z[src]+b2, z[dst]+b2) over 64 dims ---
__global__ void k_decode(const int* __restrict__ src, const int* __restrict__ dst,
                         int E, const float* __restrict__ z,
                         const float* __restrict__ b2, float* __restrict__ out) {
    long t = (long)blockIdx.x * blockDim.x + threadIdx.x;
    int e = (int)(t >> 4);
    int l = (int)(t & 15);
    if (e >= E) return;
    const int s = src[e], d = dst[e];
    const float4 zs = *(const float4*)&z[(size_t)s * F2 + l * 4];
    const float4 zd = *(const float4*)&z[(size_t)d * F2 + l * 4];
    const float4 bb = *(const float4*)&b2[l * 4];
    float v = (zs.x + bb.x) * (zd.x + bb.x)
            + (zs.y + bb.y) * (zd.y + bb.y)
            + (zs.z + bb.z) * (zd.z + bb.z)
            + (zs.w + bb.w) * (zd.w + bb.w);
#pragma unroll
    for (int off = 8; off; off >>= 1) v += __shfl_down(v, off, 16);
    if (l == 0) out[e] = v;
}

extern "C" void kernel_launch(void* const* d_in, const int* in_sizes, int n_in,
                              void* d_out, int out_size, void* d_ws, size_t ws_size,
                              hipStream_t stream) {
    const float* x  = (const float*)d_in[0];
    const float* W1 = (const float*)d_in[1];
    const float* b1 = (const float*)d_in[2];
    const float* W2 = (const float*)d_in[3];
    const float* b2 = (const float*)d_in[4];
    const int*   ei = (const int*)d_in[5];
    const int E = in_sizes[5] / 2;
    const int* rowp = ei;        // edge_index[0] = source (gather side)
    const int* colp = ei + E;    // edge_index[1] = destination (scatter side)

    // ---- workspace layout ----
    char* wsb = (char*)d_ws;
    float* dinv   = (float*)wsb;                    wsb += 100352 * 4;
    int*   cnt    = (int*)wsb;                      wsb += 100352 * 4;
    int*   ptr    = (int*)wsb;                      wsb += 100352 * 4;
    int*   cursor = (int*)wsb;                      wsb += 100352 * 4;
    int*   part   = (int*)wsb;                      wsb += 512 * 4;
    int*   idx    = (int*)wsb;                      wsb += (size_t)E * 4;
    unsigned short* W1T = (unsigned short*)wsb;     wsb += 128 * 512 * 2;
    unsigned short* hbf = (unsigned short*)wsb;     wsb += (size_t)NN * F1 * 2;  // bf16 h; reused for z
    float* agg1   = (float*)wsb;                    wsb += (size_t)NN * F1 * 4;
    float* h2     = (float*)wsb;                    wsb += (size_t)NN * F2 * 4;
    float* z      = (float*)(hbf + 0);              // 25.6MB fp32 fits in hbf's 25.6MB? no: NN*F1*2 = 25.6MB, z needs NN*F2*4 = 25.6MB — exact fit
    float* out    = (float*)d_out;

    // ---- CSR build ----
    hipMemsetAsync(cnt, 0, (size_t)NN * sizeof(int), stream);
    k_hist<<<(E + 255) / 256, 256, 0, stream>>>(colp, E, cnt);
    k_scan1<<<NB, 256, 0, stream>>>(cnt, ptr, part, dinv);
    k_scan2<<<1, 512, 0, stream>>>(part, NB);
    k_scan3<<<NB, 256, 0, stream>>>(ptr, part, cursor);
    k_fill<<<(E + 255) / 256, 256, 0, stream>>>(rowp, colp, E, cursor, idx);

    // ---- layer 1 ----
    k_w1t<<<256, 256, 0, stream>>>(W1, W1T);
    k_gemm1_mfma<<<(NN + 127) / 128, 256, 0, stream>>>(x, W1T, hbf);
    k_agg_pull<F1, unsigned short><<<(NN + 1) / 2, 256, 0, stream>>>(
        ptr, idx, E, dinv, hbf, agg1);

    // ---- layer 2 ----
    k_gemm2<<<(NN + 63) / 64, 256, 0, stream>>>(agg1, b1, W2, h2);
    k_agg_pull<F2, float><<<(NN + 3) / 4, 256, 0, stream>>>(
        ptr, idx, E, dinv, h2, z);

    // ---- decode ----
    const long dthreads = (long)E * 16;
    k_decode<<<(int)((dthreads + 255) / 256), 256, 0, stream>>>(
        rowp, colp, E, z, b2, out);
}

// Round 4
// 1089.214 us; speedup vs baseline: 2.8366x; 1.2288x over previous
//
#include <hip/hip_runtime.h>

#define NN 100000      // nodes
#define K1 500         // input features
#define F1 128         // hidden features
#define F2 64          // output features

// ---- CSR build via two-level counting sort ----
#define NBLK   128                  // edge-chunk blocks for pa/pc
#define BSH    7                    // 128 cols per coarse bucket
#define NBUCK  ((NN + 127) >> 7)    // 782
#define NBUCKP 784
#define CAP    6144                 // max edges per bucket (mean 4096, sigma ~64)

typedef __attribute__((ext_vector_type(8))) short short8;
typedef __attribute__((ext_vector_type(4))) float floatx4;

static __device__ __forceinline__ unsigned short f2bf(float f) {
    unsigned int u = __float_as_uint(f);
    unsigned int r = (u + 0x7FFF + ((u >> 16) & 1)) >> 16;   // RNE
    return (unsigned short)r;
}
static __device__ __forceinline__ float ldh(const unsigned short* p) {
    return __uint_as_float(((unsigned int)*p) << 16);
}
static __device__ __forceinline__ float ldh(const float* p) { return *p; }

// ---------------- Pass A: per-block coarse histogram ----------------
__global__ __launch_bounds__(256) void k_pa(const int* __restrict__ col, int E, int chunk,
                                            int* __restrict__ HT) {
    __shared__ int hist[NBUCKP];
    for (int i = threadIdx.x; i < NBUCKP; i += 256) hist[i] = 0;
    __syncthreads();
    const int b = blockIdx.x;
    const int s = b * chunk;
    const int e0 = min(E, s + chunk);
    for (int e = s + threadIdx.x; e < e0; e += 256)
        atomicAdd(&hist[col[e] >> BSH], 1);
    __syncthreads();
    for (int i = threadIdx.x; i < NBUCK; i += 256)
        HT[i * NBLK + b] = hist[i];
}

// ---------------- bucket sums ----------------
__global__ __launch_bounds__(128) void k_bsum(const int* __restrict__ HT, int* __restrict__ S) {
    __shared__ int s[128];
    const int tid = threadIdx.x;
    s[tid] = HT[blockIdx.x * NBLK + tid];
    __syncthreads();
    for (int off = 64; off; off >>= 1) {
        if (tid < off) s[tid] += s[tid + off];
        __syncthreads();
    }
    if (tid == 0) S[blockIdx.x] = s[0];
}

// ---------------- exclusive scan of bucket sums (single block) -------------
__global__ __launch_bounds__(1024) void k_bscan(const int* __restrict__ S,
                                                int* __restrict__ BB, int nb, int E) {
    __shared__ int s[1024];
    const int tid = threadIdx.x;
    int v = (tid < nb) ? S[tid] : 0;
    s[tid] = v;
    __syncthreads();
    for (int off = 1; off < 1024; off <<= 1) {
        int t = (tid >= off) ? s[tid - off] : 0;
        __syncthreads();
        s[tid] += t;
        __syncthreads();
    }
    if (tid < nb) BB[tid] = s[tid] - v;
    if (tid == 0) BB[nb] = E;
}

// ---------------- per-(bucket,block) absolute offsets ----------------------
__global__ __launch_bounds__(128) void k_boff(int* __restrict__ HT, const int* __restrict__ BB) {
    __shared__ int s[128];
    const int tid = threadIdx.x;
    const int rowb = blockIdx.x * NBLK;
    int v = HT[rowb + tid];
    s[tid] = v;
    __syncthreads();
    for (int off = 1; off < 128; off <<= 1) {
        int t = (tid >= off) ? s[tid - off] : 0;
        __syncthreads();
        s[tid] += t;
        __syncthreads();
    }
    HT[rowb + tid] = s[tid] - v + BB[blockIdx.x];
}

// ---------------- Pass C: distribute into coarse buckets (8B pairs) --------
__global__ __launch_bounds__(256) void k_pc(const int* __restrict__ row,
                                            const int* __restrict__ col, int E, int chunk,
                                            const int* __restrict__ HT,
                                            unsigned long long* __restrict__ pairs) {
    __shared__ int cur[NBUCKP];
    const int b = blockIdx.x;
    for (int i = threadIdx.x; i < NBUCK; i += 256) cur[i] = HT[i * NBLK + b];
    __syncthreads();
    const int s = b * chunk;
    const int e0 = min(E, s + chunk);
    for (int e = s + threadIdx.x; e < e0; e += 256) {
        const int r = row[e], c = col[e];
        const int p = atomicAdd(&cur[c >> BSH], 1);
        pairs[p] = ((unsigned long long)(unsigned)c << 32) | (unsigned)r;
    }
}

// ---------------- Pass D: fine sort within bucket + ptr/dinv ----------------
__global__ __launch_bounds__(256) void k_pd(const unsigned long long* __restrict__ pairs,
                                            const int* __restrict__ BB,
                                            int* __restrict__ ptr, float* __restrict__ dinv,
                                            int* __restrict__ idx) {
    __shared__ int colcnt[128], colptr[128], cur[128];
    __shared__ int lidx[CAP];
    const int buck = blockIdx.x;
    const int base = BB[buck];
    int count = BB[buck + 1] - base;
    if (count > CAP) count = CAP;      // paranoia (uniform randint: never hit)
    const int lo = buck << BSH;
    const int tid = threadIdx.x;
    if (tid < 128) colcnt[tid] = 0;
    __syncthreads();
    for (int e = tid; e < count; e += 256) {
        const int c = (int)(pairs[base + e] >> 32);
        atomicAdd(&colcnt[c & 127], 1);
    }
    __syncthreads();
    if (tid < 128) colptr[tid] = colcnt[tid];
    __syncthreads();
    for (int off = 1; off < 128; off <<= 1) {
        int t = 0;
        if (tid < 128 && tid >= off) t = colptr[tid - off];
        __syncthreads();
        if (tid < 128) colptr[tid] += t;
        __syncthreads();
    }
    if (tid < 128) {
        const int excl = colptr[tid] - colcnt[tid];
        cur[tid] = excl;
        const int c = lo + tid;
        if (c < NN) {
            ptr[c]  = base + excl;
            dinv[c] = rsqrtf((float)colcnt[tid] + 1.0f);   // +1 self loop
        }
    }
    __syncthreads();
    for (int e = tid; e < count; e += 256) {
        const unsigned long long pr = pairs[base + e];
        const int c = (int)(pr >> 32);
        const int p = atomicAdd(&cur[c & 127], 1);
        lidx[p] = (int)(pr & 0xffffffffu);
    }
    __syncthreads();
    for (int e = tid; e < count; e += 256)
        idx[base + e] = lidx[e];
}

// ---------------- W1T: [500][128] fp32 -> [128][512] bf16 (zero pad) -------
__global__ __launch_bounds__(256) void k_w1t(const float* __restrict__ W1,
                                             unsigned short* __restrict__ W1T) {
    int t = blockIdx.x * 256 + threadIdx.x;   // 128*512 = 65536
    int n = t >> 9, k = t & 511;
    W1T[t] = (k < K1) ? f2bf(W1[k * F1 + n]) : (unsigned short)0;
}

// ---------------- GEMM1 (MFMA bf16): h[NN,128] = x[NN,500] @ W1 ------------
__global__ __launch_bounds__(256) void k_gemm1_mfma(
    const float* __restrict__ x,
    const unsigned short* __restrict__ W1T,   // [128][512] bf16
    unsigned short* __restrict__ h)           // [NN][128] bf16
{
    const int wave = threadIdx.x >> 6;
    const int lane = threadIdx.x & 63;
    const int q    = lane >> 4;          // quad: k-offset q*8
    const int m16  = lane & 15;
    const int rowBase = blockIdx.x * 128 + wave * 32;

    floatx4 acc[2][8];
#pragma unroll
    for (int a = 0; a < 2; ++a)
#pragma unroll
        for (int b = 0; b < 8; ++b) acc[a][b] = (floatx4){0.f, 0.f, 0.f, 0.f};

    int row0 = rowBase + m16;      if (row0 > NN - 1) row0 = NN - 1;
    int row1 = rowBase + 16 + m16; if (row1 > NN - 1) row1 = NN - 1;
    const size_t rb[2] = {(size_t)row0 * K1, (size_t)row1 * K1};

#pragma unroll 3
    for (int k0 = 0; k0 < 480; k0 += 32) {
        const int kk = k0 + q * 8;
        short8 afr[2], bfr[8];
#pragma unroll
        for (int mt = 0; mt < 2; ++mt) {
            const floatx4 v0 = *(const floatx4*)(x + rb[mt] + kk);
            const floatx4 v1 = *(const floatx4*)(x + rb[mt] + kk + 4);
            short8 t;
            t[0] = f2bf(v0[0]); t[1] = f2bf(v0[1]); t[2] = f2bf(v0[2]); t[3] = f2bf(v0[3]);
            t[4] = f2bf(v1[0]); t[5] = f2bf(v1[1]); t[6] = f2bf(v1[2]); t[7] = f2bf(v1[3]);
            afr[mt] = t;
        }
#pragma unroll
        for (int nt = 0; nt < 8; ++nt)
            bfr[nt] = *(const short8*)(W1T + (nt * 16 + m16) * 512 + kk);
#pragma unroll
        for (int mt = 0; mt < 2; ++mt)
#pragma unroll
            for (int nt = 0; nt < 8; ++nt)
                acc[mt][nt] = __builtin_amdgcn_mfma_f32_16x16x32_bf16(
                    afr[mt], bfr[nt], acc[mt][nt], 0, 0, 0);
    }
    {   // K epilogue: k0 = 480, mask k >= 500 (W1T pad is already zero)
        const int kk = 480 + q * 8;
        short8 afr[2], bfr[8];
#pragma unroll
        for (int mt = 0; mt < 2; ++mt) {
            short8 t;
#pragma unroll
            for (int j = 0; j < 8; ++j) {
                const int k = kk + j;
                t[j] = (k < K1) ? (short)f2bf(x[rb[mt] + k]) : (short)0;
            }
            afr[mt] = t;
        }
#pragma unroll
        for (int nt = 0; nt < 8; ++nt)
            bfr[nt] = *(const short8*)(W1T + (nt * 16 + m16) * 512 + kk);
#pragma unroll
        for (int mt = 0; mt < 2; ++mt)
#pragma unroll
            for (int nt = 0; nt < 8; ++nt)
                acc[mt][nt] = __builtin_amdgcn_mfma_f32_16x16x32_bf16(
                    afr[mt], bfr[nt], acc[mt][nt], 0, 0, 0);
    }
    // store: C/D layout col = lane&15, row = q*4 + reg
#pragma unroll
    for (int mt = 0; mt < 2; ++mt) {
        const int rbase = rowBase + mt * 16 + q * 4;
#pragma unroll
        for (int nt = 0; nt < 8; ++nt) {
            const int col = nt * 16 + m16;
#pragma unroll
            for (int r = 0; r < 4; ++r) {
                const int row = rbase + r;
                if (row < NN) h[(size_t)row * F1 + col] = f2bf(acc[mt][nt][r]);
            }
        }
    }
}

// ---------------- pull aggregation ----------------
template <int F, typename T>
__global__ __launch_bounds__(256) void k_agg_pull(const int* __restrict__ ptr,
                                                  const int* __restrict__ idx, int E,
                                                  const float* __restrict__ dinv,
                                                  const T* __restrict__ h,
                                                  float* __restrict__ agg) {
    constexpr int NPB = 256 / F;                 // nodes per block
    const int c = blockIdx.x * NPB + threadIdx.x / F;
    const int f = threadIdx.x % F;
    if (c >= NN) return;
    const float dc = dinv[c];
    const int s   = ptr[c];
    const int end = (c + 1 < NN) ? ptr[c + 1] : E;
    float acc = ldh(&h[(size_t)c * F + f]) * dc * dc;  // self loop
    int e = s;
    for (; e + 4 <= end; e += 4) {
        const int r0 = idx[e], r1 = idx[e + 1], r2 = idx[e + 2], r3 = idx[e + 3];
        const float w0 = dinv[r0] * dc, w1 = dinv[r1] * dc;
        const float w2 = dinv[r2] * dc, w3 = dinv[r3] * dc;
        acc += ldh(&h[(size_t)r0 * F + f]) * w0;
        acc += ldh(&h[(size_t)r1 * F + f]) * w1;
        acc += ldh(&h[(size_t)r2 * F + f]) * w2;
        acc += ldh(&h[(size_t)r3 * F + f]) * w3;
    }
    for (; e < end; ++e) {
        const int r = idx[e];
        acc += ldh(&h[(size_t)r * F + f]) * (dinv[r] * dc);
    }
    agg[(size_t)c * F + f] = acc;
}

// ---------------- GEMM2: h2[NN,64] = relu(agg1 + b1) @ W2[128,64] -----------
__global__ __launch_bounds__(256) void k_gemm2(const float* __restrict__ agg1,
                                               const float* __restrict__ b1,
                                               const float* __restrict__ W2,
                                               float* __restrict__ h2) {
    __shared__ __align__(16) float W2s[F1 * F2];
    __shared__ __align__(16) float xs[64 * F1];
    const int tid = threadIdx.x;
    const int r0  = blockIdx.x * 64;
    for (int i = tid; i < F1 * F2; i += 256) W2s[i] = W2[i];
    const int base = r0 * F1;
    for (int i = tid; i < 64 * F1; i += 256) {
        int gi = base + i;
        float v = 0.f;
        if (gi < NN * F1) v = fmaxf(agg1[gi] + b1[i & (F1 - 1)], 0.f);
        xs[i] = v;
    }
    __syncthreads();

    const int j = tid & 63;      // output column
    const int g = tid >> 6;      // wave id -> rows g*16 .. g*16+15
    float acc[16];
#pragma unroll
    for (int rr = 0; rr < 16; ++rr) acc[rr] = 0.f;

    for (int k = 0; k < F1; k += 4) {
        const float w0 = W2s[(k + 0) * F2 + j];
        const float w1 = W2s[(k + 1) * F2 + j];
        const float w2 = W2s[(k + 2) * F2 + j];
        const float w3 = W2s[(k + 3) * F2 + j];
#pragma unroll
        for (int rr = 0; rr < 16; ++rr) {
            const float4 xv = *(const float4*)&xs[(g * 16 + rr) * F1 + k];
            acc[rr] += xv.x * w0 + xv.y * w1 + xv.z * w2 + xv.w * w3;
        }
    }
#pragma unroll
    for (int rr = 0; rr < 16; ++rr) {
        int r = r0 + g * 16 + rr;
        if (r < NN) h2[(size_t)r * F2 + j] = acc[rr];
    }
}

// ---------------- decode: out[e] = dot(z[src]+b2, z[dst]+b2) over 64 dims ---
__global__ void k_decode(const int* __restrict__ src, const int* __restrict__ dst,
                         int E, const float* __restrict__ z,
                         const float* __restrict__ b2, float* __restrict__ out) {
    long t = (long)blockIdx.x * blockDim.x + threadIdx.x;
    int e = (int)(t >> 4);
    int l = (int)(t & 15);
    if (e >= E) return;
    const int s = src[e], d = dst[e];
    const float4 zs = *(const float4*)&z[(size_t)s * F2 + l * 4];
    const float4 zd = *(const float4*)&z[(size_t)d * F2 + l * 4];
    const float4 bb = *(const float4*)&b2[l * 4];
    float v = (zs.x + bb.x) * (zd.x + bb.x)
            + (zs.y + bb.y) * (zd.y + bb.y)
            + (zs.z + bb.z) * (zd.z + bb.z)
            + (zs.w + bb.w) * (zd.w + bb.w);
#pragma unroll
    for (int off = 8; off; off >>= 1) v += __shfl_down(v, off, 16);
    if (l == 0) out[e] = v;
}

extern "C" void kernel_launch(void* const* d_in, const int* in_sizes, int n_in,
                              void* d_out, int out_size, void* d_ws, size_t ws_size,
                              hipStream_t stream) {
    const float* x  = (const float*)d_in[0];
    const float* W1 = (const float*)d_in[1];
    const float* b1 = (const float*)d_in[2];
    const float* W2 = (const float*)d_in[3];
    const float* b2 = (const float*)d_in[4];
    const int*   ei = (const int*)d_in[5];
    const int E = in_sizes[5] / 2;
    const int* rowp = ei;        // edge_index[0] = source (gather side)
    const int* colp = ei + E;    // edge_index[1] = destination (scatter side)

    // ---- workspace layout (all sub-offsets multiple of 8 bytes) ----
    char* wsb = (char*)d_ws;
    float* dinv = (float*)wsb;                 wsb += 100352 * 4;
    int*   ptr  = (int*)wsb;                   wsb += 100352 * 4;
    int*   S    = (int*)wsb;                   wsb += 1024 * 4;
    int*   BB   = (int*)wsb;                   wsb += 1024 * 4;
    int*   HT   = (int*)wsb;                   wsb += (size_t)1024 * NBLK * 4;
    int*   idx  = (int*)wsb;                   wsb += (size_t)E * 4;
    unsigned short* W1T = (unsigned short*)wsb; wsb += 128 * 512 * 2;
    unsigned short* hbf = (unsigned short*)wsb; wsb += (size_t)NN * F1 * 2;  // h bf16; reused as z
    float* agg1 = (float*)wsb;                 wsb += (size_t)NN * F1 * 4;
    float* h2   = (float*)wsb;                 wsb += (size_t)NN * F2 * 4;
    unsigned long long* pairs = (unsigned long long*)agg1;  // dead before agg1 written
    float* z    = (float*)hbf;                              // dead before z written
    float* out  = (float*)d_out;

    const int chunk = (E + NBLK - 1) / NBLK;

    // ---- CSR build (counting sort, no global atomics, no memsets) ----
    k_pa   <<<NBLK, 256, 0, stream>>>(colp, E, chunk, HT);
    k_bsum <<<NBUCK, 128, 0, stream>>>(HT, S);
    k_bscan<<<1, 1024, 0, stream>>>(S, BB, NBUCK, E);
    k_boff <<<NBUCK, 128, 0, stream>>>(HT, BB);
    k_pc   <<<NBLK, 256, 0, stream>>>(rowp, colp, E, chunk, HT, pairs);
    k_pd   <<<NBUCK, 256, 0, stream>>>(pairs, BB, ptr, dinv, idx);

    // ---- layer 1 ----
    k_w1t<<<256, 256, 0, stream>>>(W1, W1T);
    k_gemm1_mfma<<<(NN + 127) / 128, 256, 0, stream>>>(x, W1T, hbf);
    k_agg_pull<F1, unsigned short><<<(NN + 1) / 2, 256, 0, stream>>>(
        ptr, idx, E, dinv, hbf, agg1);

    // ---- layer 2 ----
    k_gemm2<<<(NN + 63) / 64, 256, 0, stream>>>(agg1, b1, W2, h2);
    k_agg_pull<F2, float><<<(NN + 3) / 4, 256, 0, stream>>>(
        ptr, idx, E, dinv, h2, z);

    // ---- decode ----
    const long dthreads = (long)E * 16;
    k_decode<<<(int)((dthreads + 255) / 256), 256, 0, stream>>>(
        rowp, colp, E, z, b2, out);
}

// Round 5
// 983.625 us; speedup vs baseline: 3.1411x; 1.1073x over previous
//
#include <hip/hip_runtime.h>

#define NN 100000      // nodes
#define K1 500         // input features
#define F1 128         // hidden features
#define F2 64          // output features

// ---- CSR build via two-level counting sort ----
#define NBLK   128                  // edge-chunk blocks for pa/pc
#define BSH    7                    // 128 cols per coarse bucket
#define NBUCK  ((NN + 127) >> 7)    // 782
#define NBUCKP 784
#define CAP    6144                 // max edges per bucket (mean 4096, sigma ~64)

typedef __attribute__((ext_vector_type(8))) short short8;
typedef __attribute__((ext_vector_type(4))) float floatx4;

static __device__ __forceinline__ unsigned short f2bf(float f) {
    unsigned int u = __float_as_uint(f);
    unsigned int r = (u + 0x7FFF + ((u >> 16) & 1)) >> 16;   // RNE
    return (unsigned short)r;
}
static __device__ __forceinline__ void bf2x(unsigned int u, float& lo, float& hi) {
    lo = __uint_as_float(u << 16);
    hi = __uint_as_float(u & 0xffff0000u);
}

// ---------------- Pass A: per-block coarse histogram ----------------
__global__ __launch_bounds__(256) void k_pa(const int* __restrict__ col, int E, int chunk,
                                            int* __restrict__ HT) {
    __shared__ int hist[NBUCKP];
    for (int i = threadIdx.x; i < NBUCKP; i += 256) hist[i] = 0;
    __syncthreads();
    const int b = blockIdx.x;
    const int s = b * chunk;
    const int e0 = min(E, s + chunk);
    for (int e = s + threadIdx.x; e < e0; e += 256)
        atomicAdd(&hist[col[e] >> BSH], 1);
    __syncthreads();
    for (int i = threadIdx.x; i < NBUCK; i += 256)
        HT[i * NBLK + b] = hist[i];
}

// ---------------- bucket sums ----------------
__global__ __launch_bounds__(128) void k_bsum(const int* __restrict__ HT, int* __restrict__ S) {
    __shared__ int s[128];
    const int tid = threadIdx.x;
    s[tid] = HT[blockIdx.x * NBLK + tid];
    __syncthreads();
    for (int off = 64; off; off >>= 1) {
        if (tid < off) s[tid] += s[tid + off];
        __syncthreads();
    }
    if (tid == 0) S[blockIdx.x] = s[0];
}

// ---------------- exclusive scan of bucket sums (single block) -------------
__global__ __launch_bounds__(1024) void k_bscan(const int* __restrict__ S,
                                                int* __restrict__ BB, int nb, int E) {
    __shared__ int s[1024];
    const int tid = threadIdx.x;
    int v = (tid < nb) ? S[tid] : 0;
    s[tid] = v;
    __syncthreads();
    for (int off = 1; off < 1024; off <<= 1) {
        int t = (tid >= off) ? s[tid - off] : 0;
        __syncthreads();
        s[tid] += t;
        __syncthreads();
    }
    if (tid < nb) BB[tid] = s[tid] - v;
    if (tid == 0) BB[nb] = E;
}

// ---------------- per-(bucket,block) absolute offsets ----------------------
__global__ __launch_bounds__(128) void k_boff(int* __restrict__ HT, const int* __restrict__ BB) {
    __shared__ int s[128];
    const int tid = threadIdx.x;
    const int rowb = blockIdx.x * NBLK;
    int v = HT[rowb + tid];
    s[tid] = v;
    __syncthreads();
    for (int off = 1; off < 128; off <<= 1) {
        int t = (tid >= off) ? s[tid - off] : 0;
        __syncthreads();
        s[tid] += t;
        __syncthreads();
    }
    HT[rowb + tid] = s[tid] - v + BB[blockIdx.x];
}

// ---------------- Pass C: distribute into coarse buckets (8B pairs) --------
__global__ __launch_bounds__(256) void k_pc(const int* __restrict__ row,
                                            const int* __restrict__ col, int E, int chunk,
                                            const int* __restrict__ HT,
                                            unsigned long long* __restrict__ pairs) {
    __shared__ int cur[NBUCKP];
    const int b = blockIdx.x;
    for (int i = threadIdx.x; i < NBUCK; i += 256) cur[i] = HT[i * NBLK + b];
    __syncthreads();
    const int s = b * chunk;
    const int e0 = min(E, s + chunk);
    for (int e = s + threadIdx.x; e < e0; e += 256) {
        const int r = row[e], c = col[e];
        const int p = atomicAdd(&cur[c >> BSH], 1);
        pairs[p] = ((unsigned long long)(unsigned)c << 32) | (unsigned)r;
    }
}

// ---------------- Pass D: fine sort within bucket + ptr/dinv ----------------
__global__ __launch_bounds__(256) void k_pd(const unsigned long long* __restrict__ pairs,
                                            const int* __restrict__ BB,
                                            int* __restrict__ ptr, float* __restrict__ dinv,
                                            int* __restrict__ idx) {
    __shared__ int colcnt[128], colptr[128], cur[128];
    __shared__ int lidx[CAP];
    const int buck = blockIdx.x;
    const int base = BB[buck];
    int count = BB[buck + 1] - base;
    if (count > CAP) count = CAP;      // paranoia (uniform randint: never hit)
    const int lo = buck << BSH;
    const int tid = threadIdx.x;
    if (tid < 128) colcnt[tid] = 0;
    __syncthreads();
    for (int e = tid; e < count; e += 256) {
        const int c = (int)(pairs[base + e] >> 32);
        atomicAdd(&colcnt[c & 127], 1);
    }
    __syncthreads();
    if (tid < 128) colptr[tid] = colcnt[tid];
    __syncthreads();
    for (int off = 1; off < 128; off <<= 1) {
        int t = 0;
        if (tid < 128 && tid >= off) t = colptr[tid - off];
        __syncthreads();
        if (tid < 128) colptr[tid] += t;
        __syncthreads();
    }
    if (tid < 128) {
        const int excl = colptr[tid] - colcnt[tid];
        cur[tid] = excl;
        const int c = lo + tid;
        if (c < NN) {
            ptr[c]  = base + excl;
            dinv[c] = rsqrtf((float)colcnt[tid] + 1.0f);   // +1 self loop
        }
    }
    __syncthreads();
    for (int e = tid; e < count; e += 256) {
        const unsigned long long pr = pairs[base + e];
        const int c = (int)(pr >> 32);
        const int p = atomicAdd(&cur[c & 127], 1);
        lidx[p] = (int)(pr & 0xffffffffu);
    }
    __syncthreads();
    for (int e = tid; e < count; e += 256)
        idx[base + e] = lidx[e];
}

// ---------------- W1T: [500][128] fp32 -> [128][512] bf16 (zero pad) -------
__global__ __launch_bounds__(256) void k_w1t(const float* __restrict__ W1,
                                             unsigned short* __restrict__ W1T) {
    int t = blockIdx.x * 256 + threadIdx.x;   // 128*512 = 65536
    int n = t >> 9, k = t & 511;
    W1T[t] = (k < K1) ? f2bf(W1[k * F1 + n]) : (unsigned short)0;
}

// ---------------- GEMM1 (MFMA bf16): h'[r] = (x @ W1)[r] * dinv[r] ---------
__global__ __launch_bounds__(256) void k_gemm1_mfma(
    const float* __restrict__ x,
    const unsigned short* __restrict__ W1T,   // [128][512] bf16
    const float* __restrict__ dinv,
    unsigned short* __restrict__ h)           // [NN][128] bf16, pre-scaled
{
    const int wave = threadIdx.x >> 6;
    const int lane = threadIdx.x & 63;
    const int q    = lane >> 4;          // quad: k-offset q*8
    const int m16  = lane & 15;
    const int rowBase = blockIdx.x * 128 + wave * 32;

    floatx4 acc[2][8];
#pragma unroll
    for (int a = 0; a < 2; ++a)
#pragma unroll
        for (int b = 0; b < 8; ++b) acc[a][b] = (floatx4){0.f, 0.f, 0.f, 0.f};

    int row0 = rowBase + m16;      if (row0 > NN - 1) row0 = NN - 1;
    int row1 = rowBase + 16 + m16; if (row1 > NN - 1) row1 = NN - 1;
    const size_t rb[2] = {(size_t)row0 * K1, (size_t)row1 * K1};

#pragma unroll 3
    for (int k0 = 0; k0 < 480; k0 += 32) {
        const int kk = k0 + q * 8;
        short8 afr[2], bfr[8];
#pragma unroll
        for (int mt = 0; mt < 2; ++mt) {
            const floatx4 v0 = *(const floatx4*)(x + rb[mt] + kk);
            const floatx4 v1 = *(const floatx4*)(x + rb[mt] + kk + 4);
            short8 t;
            t[0] = f2bf(v0[0]); t[1] = f2bf(v0[1]); t[2] = f2bf(v0[2]); t[3] = f2bf(v0[3]);
            t[4] = f2bf(v1[0]); t[5] = f2bf(v1[1]); t[6] = f2bf(v1[2]); t[7] = f2bf(v1[3]);
            afr[mt] = t;
        }
#pragma unroll
        for (int nt = 0; nt < 8; ++nt)
            bfr[nt] = *(const short8*)(W1T + (nt * 16 + m16) * 512 + kk);
#pragma unroll
        for (int mt = 0; mt < 2; ++mt)
#pragma unroll
            for (int nt = 0; nt < 8; ++nt)
                acc[mt][nt] = __builtin_amdgcn_mfma_f32_16x16x32_bf16(
                    afr[mt], bfr[nt], acc[mt][nt], 0, 0, 0);
    }
    {   // K epilogue: k0 = 480, mask k >= 500 (W1T pad is already zero)
        const int kk = 480 + q * 8;
        short8 afr[2], bfr[8];
#pragma unroll
        for (int mt = 0; mt < 2; ++mt) {
            short8 t;
#pragma unroll
            for (int j = 0; j < 8; ++j) {
                const int k = kk + j;
                t[j] = (k < K1) ? (short)f2bf(x[rb[mt] + k]) : (short)0;
            }
            afr[mt] = t;
        }
#pragma unroll
        for (int nt = 0; nt < 8; ++nt)
            bfr[nt] = *(const short8*)(W1T + (nt * 16 + m16) * 512 + kk);
#pragma unroll
        for (int mt = 0; mt < 2; ++mt)
#pragma unroll
            for (int nt = 0; nt < 8; ++nt)
                acc[mt][nt] = __builtin_amdgcn_mfma_f32_16x16x32_bf16(
                    afr[mt], bfr[nt], acc[mt][nt], 0, 0, 0);
    }
    // store: C/D layout col = lane&15, row = q*4 + reg; scale by dinv[row]
#pragma unroll
    for (int mt = 0; mt < 2; ++mt) {
        const int rbase = rowBase + mt * 16 + q * 4;
#pragma unroll
        for (int r = 0; r < 4; ++r) {
            const int row = rbase + r;
            if (row < NN) {
                const float dr = dinv[row];
#pragma unroll
                for (int nt = 0; nt < 8; ++nt)
                    h[(size_t)row * F1 + nt * 16 + m16] = f2bf(acc[mt][nt][r] * dr);
            }
        }
    }
}

// ---------------- agg1: agg[c] = dinv[c] * (sum h'[r] + h'[c]), h' bf16 ----
// one wave per node; lane = es*16 + fg; fg covers 8 feats via uint4 (16B)
__global__ __launch_bounds__(256) void k_agg1(const int* __restrict__ ptr,
                                              const int* __restrict__ idx, int E,
                                              const float* __restrict__ dinv,
                                              const unsigned short* __restrict__ h,
                                              float* __restrict__ agg) {
    const int c    = blockIdx.x * 4 + (threadIdx.x >> 6);
    const int lane = threadIdx.x & 63;
    const int es = lane >> 4, fg = lane & 15;
    float acc[8] = {0.f,0.f,0.f,0.f,0.f,0.f,0.f,0.f};
    if (es == 0) {  // self loop
        const uint4 u = *(const uint4*)(h + (size_t)c * F1 + fg * 8);
        bf2x(u.x, acc[0], acc[1]);
        bf2x(u.y, acc[2], acc[3]);
        bf2x(u.z, acc[4], acc[5]);
        bf2x(u.w, acc[6], acc[7]);
    }
    const int s   = ptr[c];
    const int end = (c + 1 < NN) ? ptr[c + 1] : E;
    int e = s + es;
    for (; e + 4 < end; e += 8) {
        const int r0 = idx[e], r1 = idx[e + 4];
        const uint4 u0 = *(const uint4*)(h + (size_t)r0 * F1 + fg * 8);
        const uint4 u1 = *(const uint4*)(h + (size_t)r1 * F1 + fg * 8);
        float lo, hi;
        bf2x(u0.x, lo, hi); acc[0] += lo; acc[1] += hi;
        bf2x(u0.y, lo, hi); acc[2] += lo; acc[3] += hi;
        bf2x(u0.z, lo, hi); acc[4] += lo; acc[5] += hi;
        bf2x(u0.w, lo, hi); acc[6] += lo; acc[7] += hi;
        bf2x(u1.x, lo, hi); acc[0] += lo; acc[1] += hi;
        bf2x(u1.y, lo, hi); acc[2] += lo; acc[3] += hi;
        bf2x(u1.z, lo, hi); acc[4] += lo; acc[5] += hi;
        bf2x(u1.w, lo, hi); acc[6] += lo; acc[7] += hi;
    }
    if (e < end) {
        const int r = idx[e];
        const uint4 u = *(const uint4*)(h + (size_t)r * F1 + fg * 8);
        float lo, hi;
        bf2x(u.x, lo, hi); acc[0] += lo; acc[1] += hi;
        bf2x(u.y, lo, hi); acc[2] += lo; acc[3] += hi;
        bf2x(u.z, lo, hi); acc[4] += lo; acc[5] += hi;
        bf2x(u.w, lo, hi); acc[6] += lo; acc[7] += hi;
    }
#pragma unroll
    for (int j = 0; j < 8; ++j) {
        acc[j] += __shfl_xor(acc[j], 16);
        acc[j] += __shfl_xor(acc[j], 32);
    }
    if (es == 0) {
        const float dc = dinv[c];
        float4 o0 = {acc[0] * dc, acc[1] * dc, acc[2] * dc, acc[3] * dc};
        float4 o1 = {acc[4] * dc, acc[5] * dc, acc[6] * dc, acc[7] * dc};
        *(float4*)(agg + (size_t)c * F1 + fg * 8)     = o0;
        *(float4*)(agg + (size_t)c * F1 + fg * 8 + 4) = o1;
    }
}

// ---------------- GEMM2: h2'[r] = (relu(agg1+b1) @ W2)[r] * dinv[r] --------
__global__ __launch_bounds__(256) void k_gemm2(const float* __restrict__ agg1,
                                               const float* __restrict__ b1,
                                               const float* __restrict__ W2,
                                               const float* __restrict__ dinv,
                                               float* __restrict__ h2) {
    __shared__ __align__(16) float W2s[F1 * F2];
    __shared__ __align__(16) float xs[64 * F1];
    const int tid = threadIdx.x;
    const int r0  = blockIdx.x * 64;
    for (int i = tid; i < F1 * F2; i += 256) W2s[i] = W2[i];
    const int base = r0 * F1;
    for (int i = tid; i < 64 * F1; i += 256) {
        int gi = base + i;
        float v = 0.f;
        if (gi < NN * F1) v = fmaxf(agg1[gi] + b1[i & (F1 - 1)], 0.f);
        xs[i] = v;
    }
    __syncthreads();

    const int j = tid & 63;      // output column
    const int g = tid >> 6;      // wave id -> rows g*16 .. g*16+15
    float acc[16];
#pragma unroll
    for (int rr = 0; rr < 16; ++rr) acc[rr] = 0.f;

    for (int k = 0; k < F1; k += 4) {
        const float w0 = W2s[(k + 0) * F2 + j];
        const float w1 = W2s[(k + 1) * F2 + j];
        const float w2 = W2s[(k + 2) * F2 + j];
        const float w3 = W2s[(k + 3) * F2 + j];
#pragma unroll
        for (int rr = 0; rr < 16; ++rr) {
            const float4 xv = *(const float4*)&xs[(g * 16 + rr) * F1 + k];
            acc[rr] += xv.x * w0 + xv.y * w1 + xv.z * w2 + xv.w * w3;
        }
    }
#pragma unroll
    for (int rr = 0; rr < 16; ++rr) {
        int r = r0 + g * 16 + rr;
        if (r < NN) h2[(size_t)r * F2 + j] = acc[rr] * dinv[r];
    }
}

// ---------------- agg2: z[c] = dinv[c] * (sum h2'[r] + h2'[c]), fp32 -------
__global__ __launch_bounds__(256) void k_agg2(const int* __restrict__ ptr,
                                              const int* __restrict__ idx, int E,
                                              const float* __restrict__ dinv,
                                              const float* __restrict__ h2,
                                              float* __restrict__ z) {
    const int c    = blockIdx.x * 4 + (threadIdx.x >> 6);
    const int lane = threadIdx.x & 63;
    const int es = lane >> 4, fg = lane & 15;
    float a0 = 0.f, a1 = 0.f, a2 = 0.f, a3 = 0.f;
    if (es == 0) {  // self loop
        const float4 v = *(const float4*)(h2 + (size_t)c * F2 + fg * 4);
        a0 = v.x; a1 = v.y; a2 = v.z; a3 = v.w;
    }
    const int s   = ptr[c];
    const int end = (c + 1 < NN) ? ptr[c + 1] : E;
    int e = s + es;
    for (; e + 4 < end; e += 8) {
        const int r0 = idx[e], r1 = idx[e + 4];
        const float4 v0 = *(const float4*)(h2 + (size_t)r0 * F2 + fg * 4);
        const float4 v1 = *(const float4*)(h2 + (size_t)r1 * F2 + fg * 4);
        a0 += v0.x + v1.x; a1 += v0.y + v1.y;
        a2 += v0.z + v1.z; a3 += v0.w + v1.w;
    }
    if (e < end) {
        const int r = idx[e];
        const float4 v = *(const float4*)(h2 + (size_t)r * F2 + fg * 4);
        a0 += v.x; a1 += v.y; a2 += v.z; a3 += v.w;
    }
    a0 += __shfl_xor(a0, 16); a0 += __shfl_xor(a0, 32);
    a1 += __shfl_xor(a1, 16); a1 += __shfl_xor(a1, 32);
    a2 += __shfl_xor(a2, 16); a2 += __shfl_xor(a2, 32);
    a3 += __shfl_xor(a3, 16); a3 += __shfl_xor(a3, 32);
    if (es == 0) {
        const float dc = dinv[c];
        float4 o = {a0 * dc, a1 * dc, a2 * dc, a3 * dc};
        *(float4*)(z + (size_t)c * F2 + fg * 4) = o;
    }
}

// ---------------- decode: out[e] = dot(z[src]+b2, z[dst]+b2) over 64 dims ---
__global__ void k_decode(const int* __restrict__ src, const int* __restrict__ dst,
                         int E, const float* __restrict__ z,
                         const float* __restrict__ b2, float* __restrict__ out) {
    long t = (long)blockIdx.x * blockDim.x + threadIdx.x;
    int e = (int)(t >> 4);
    int l = (int)(t & 15);
    if (e >= E) return;
    const int s = src[e], d = dst[e];
    const float4 zs = *(const float4*)&z[(size_t)s * F2 + l * 4];
    const float4 zd = *(const float4*)&z[(size_t)d * F2 + l * 4];
    const float4 bb = *(const float4*)&b2[l * 4];
    float v = (zs.x + bb.x) * (zd.x + bb.x)
            + (zs.y + bb.y) * (zd.y + bb.y)
            + (zs.z + bb.z) * (zd.z + bb.z)
            + (zs.w + bb.w) * (zd.w + bb.w);
#pragma unroll
    for (int off = 8; off; off >>= 1) v += __shfl_down(v, off, 16);
    if (l == 0) out[e] = v;
}

extern "C" void kernel_launch(void* const* d_in, const int* in_sizes, int n_in,
                              void* d_out, int out_size, void* d_ws, size_t ws_size,
                              hipStream_t stream) {
    const float* x  = (const float*)d_in[0];
    const float* W1 = (const float*)d_in[1];
    const float* b1 = (const float*)d_in[2];
    const float* W2 = (const float*)d_in[3];
    const float* b2 = (const float*)d_in[4];
    const int*   ei = (const int*)d_in[5];
    const int E = in_sizes[5] / 2;
    const int* rowp = ei;        // edge_index[0] = source (gather side)
    const int* colp = ei + E;    // edge_index[1] = destination (scatter side)

    // ---- workspace layout (all sub-offsets multiple of 16 bytes) ----
    char* wsb = (char*)d_ws;
    float* dinv = (float*)wsb;                 wsb += 100352 * 4;
    int*   ptr  = (int*)wsb;                   wsb += 100352 * 4;
    int*   S    = (int*)wsb;                   wsb += 1024 * 4;
    int*   BB   = (int*)wsb;                   wsb += 1024 * 4;
    int*   HT   = (int*)wsb;                   wsb += (size_t)1024 * NBLK * 4;
    int*   idx  = (int*)wsb;                   wsb += (size_t)E * 4;
    unsigned short* W1T = (unsigned short*)wsb; wsb += 128 * 512 * 2;
    unsigned short* hbf = (unsigned short*)wsb; wsb += (size_t)NN * F1 * 2;  // h' bf16; reused as z
    float* agg1 = (float*)wsb;                 wsb += (size_t)NN * F1 * 4;
    float* h2   = (float*)wsb;                 wsb += (size_t)NN * F2 * 4;
    unsigned long long* pairs = (unsigned long long*)agg1;  // dead before agg1 written
    float* z    = (float*)hbf;                              // dead before z written
    float* out  = (float*)d_out;

    const int chunk = (E + NBLK - 1) / NBLK;

    // ---- CSR build (counting sort, no global atomics, no memsets) ----
    k_pa   <<<NBLK, 256, 0, stream>>>(colp, E, chunk, HT);
    k_bsum <<<NBUCK, 128, 0, stream>>>(HT, S);
    k_bscan<<<1, 1024, 0, stream>>>(S, BB, NBUCK, E);
    k_boff <<<NBUCK, 128, 0, stream>>>(HT, BB);
    k_pc   <<<NBLK, 256, 0, stream>>>(rowp, colp, E, chunk, HT, pairs);
    k_pd   <<<NBUCK, 256, 0, stream>>>(pairs, BB, ptr, dinv, idx);

    // ---- layer 1 ----
    k_w1t<<<256, 256, 0, stream>>>(W1, W1T);
    k_gemm1_mfma<<<(NN + 127) / 128, 256, 0, stream>>>(x, W1T, dinv, hbf);
    k_agg1<<<NN / 4, 256, 0, stream>>>(ptr, idx, E, dinv, hbf, agg1);

    // ---- layer 2 ----
    k_gemm2<<<(NN + 63) / 64, 256, 0, stream>>>(agg1, b1, W2, dinv, h2);
    k_agg2<<<NN / 4, 256, 0, stream>>>(ptr, idx, E, dinv, h2, z);

    // ---- decode ----
    const long dthreads = (long)E * 16;
    k_decode<<<(int)((dthreads + 255) / 256), 256, 0, stream>>>(
        rowp, colp, E, z, b2, out);
}